// Round 1
// 9886.924 us; speedup vs baseline: 1.0105x; 1.0105x over previous
//
#include <hip/hip_runtime.h>
#include <stdint.h>

// Problem dims (fixed by reference)
#define BB 512      // batch
#define SS 256      // seq
#define EE 128      // embed
#define HH 128      // hidden
#define TT 128      // decode steps
#define G4 512      // 4*H

#define NEG_INF_F (-1e30f)
#define TINY_F32  1.17549435e-38f

// ---------------- threefry2x32 (JAX-exact, 20 rounds) ----------------
__device__ __forceinline__ uint32_t rotl32(uint32_t v, int r){ return (v<<r)|(v>>(32-r)); }

__device__ __forceinline__ void threefry2x32(uint32_t k0, uint32_t k1,
                                             uint32_t c0, uint32_t c1,
                                             uint32_t* o0, uint32_t* o1){
  uint32_t ks2 = k0 ^ k1 ^ 0x1BD11BDAu;
  uint32_t x0 = c0 + k0;
  uint32_t x1 = c1 + k1;
#define TF_R(rr) { x0 += x1; x1 = rotl32(x1, rr); x1 ^= x0; }
  TF_R(13) TF_R(15) TF_R(26) TF_R(6)
  x0 += k1; x1 += ks2 + 1u;
  TF_R(17) TF_R(29) TF_R(16) TF_R(24)
  x0 += ks2; x1 += k0 + 2u;
  TF_R(13) TF_R(15) TF_R(26) TF_R(6)
  x0 += k0; x1 += k1 + 3u;
  TF_R(17) TF_R(29) TF_R(16) TF_R(24)
  x0 += k1; x1 += ks2 + 4u;
  TF_R(13) TF_R(15) TF_R(26) TF_R(6)
  x0 += ks2; x1 += k0 + 5u;
#undef TF_R
  *o0 = x0; *o1 = x1;
}

// ---------------- XLA CPU f32 tanh expansion ----------------
__device__ __forceinline__ float xla_tanhf(float x){
#pragma clang fp contract(off)
  float ax = fabsf(x);
  float xc = fminf(fmaxf(x, -9.0f), 9.0f);
  float x2 = xc*xc;
  float num = -2.76076847742355e-16f;
  num = x2*num + 2.00018790482477e-13f;
  num = x2*num + -8.60467152213735e-11f;
  num = x2*num + 5.12229709037114e-08f;
  num = x2*num + 1.48572235717979e-05f;
  num = x2*num + 6.37261928875436e-04f;
  num = x2*num + 4.89352455891786e-03f;
  num = xc*num;
  float den = 1.19825839466702e-06f;
  den = x2*den + 1.18534705686654e-04f;
  den = x2*den + 2.26843463243900e-03f;
  den = x2*den + 4.89352518554385e-03f;
  return (ax < 4e-4f) ? x : (num/den);
}

__device__ __forceinline__ float xla_sigmoidf(float x){
#pragma clang fp contract(off)
  return 0.5f + 0.5f * xla_tanhf(0.5f * x);
}

__device__ __forceinline__ double wave_sum_f64(double v){
  #pragma unroll
  for (int off = 32; off; off >>= 1) v += __shfl_xor(v, off, 64);
  return v;
}

// ---------------- e_g / e_p precompute (runs once) ----------------
__global__ __launch_bounds__(256) void precompute_e_kernel(
    const float* __restrict__ ctx, const float* __restrict__ W,
    const float* __restrict__ bias, float* __restrict__ e_out)
{
#pragma clang fp contract(off)
  __shared__ float Ct[64][65];
  __shared__ float Wt[128][65];
  const int tid = threadIdx.x;
  const int tx = tid & 31;
  const int ty = tid >> 5;
  const size_t r0 = (size_t)blockIdx.x * 64;

  double acc[8][4];
  #pragma unroll
  for (int i=0;i<8;++i){
    #pragma unroll
    for (int j=0;j<4;++j) acc[i][j]=0.0;
  }

  for (int kc=0; kc<2; ++kc){
    for (int idx = tid; idx < 64*64; idx += 256){
      const int row = idx >> 6, col = idx & 63;
      Ct[row][col] = ctx[(r0 + row)*HH + kc*64 + col];
    }
    for (int idx = tid; idx < 128*64; idx += 256){
      const int row = idx >> 6, col = idx & 63;
      Wt[row][col] = W[row*HH + kc*64 + col];
    }
    __syncthreads();
    #pragma unroll 4
    for (int kk=0; kk<64; ++kk){
      float cv[8], wv[4];
      #pragma unroll
      for (int i=0;i<8;++i) cv[i] = Ct[ty + 8*i][kk];
      #pragma unroll
      for (int j=0;j<4;++j) wv[j] = Wt[tx + 32*j][kk];
      #pragma unroll
      for (int i=0;i<8;++i){
        #pragma unroll
        for (int j=0;j<4;++j) acc[i][j] += (double)cv[i] * (double)wv[j];
      }
    }
    __syncthreads();
  }
  #pragma unroll
  for (int i=0;i<8;++i){
    const size_t r = r0 + ty + 8*i;
    const int s  = (int)(r >> 9);
    const int bb = (int)(r & 511);
    float* dst = e_out + ((size_t)bb*SS + s)*HH;
    #pragma unroll
    for (int j=0;j<4;++j){
      const int c = tx + 32*j;
      dst[c] = (float)acc[i][j] + bias[c];
    }
  }
}

// ---------------- weight transpose (runs once) ----------------
__global__ void transpose_weights_kernel(
    const float* __restrict__ Wi, const float* __restrict__ Wh,
    const float* __restrict__ Wqg, const float* __restrict__ Wqp,
    float* __restrict__ WiT, float* __restrict__ WhT,
    float* __restrict__ WqgT, float* __restrict__ WqpT)
{
  const int i = blockIdx.x * blockDim.x + threadIdx.x;
  if (i < G4*EE){
    const int j = i / EE, e = i % EE;
    WiT[e*G4 + j] = Wi[i];
    WhT[e*G4 + j] = Wh[i];
  }
  if (i < HH*HH){
    const int o = i / HH, h = i % HH;
    WqgT[h*HH + o] = Wqg[i];
    WqpT[h*HH + o] = Wqp[i];
  }
}

// ---------------- fused decode: 1024 threads/block, one block per batch element ----------------
// Bank-conflict fix this round: q/vg/vp are replicated into 4 bank-shifted copies
// (row stride 132 => copy c's reads land on bank (4c + 16cc + i) % 32 -> the 4
// quarter-groups of a wave hit 4 DISTINCT banks instead of serializing 4-way on one).
// Values read are identical; all summation orders unchanged -> bit-identical results.
__global__ __launch_bounds__(1024, 4) void decode_kernel(
    const float* __restrict__ dec0, const float* __restrict__ h0v, const float* __restrict__ c0v,
    const float* __restrict__ WiT, const float* __restrict__ WhT,
    const float* __restrict__ bi, const float* __restrict__ bh,
    const float* __restrict__ WqgT, const float* __restrict__ bqg, const float* __restrict__ vg,
    const float* __restrict__ WqpT, const float* __restrict__ bqp, const float* __restrict__ vp,
    const float* __restrict__ e_g, const float* __restrict__ e_p,
    const float* __restrict__ emb,
    float* __restrict__ probs_out, float* __restrict__ sels_out,
    float* __restrict__ hx_out, float* __restrict__ cx_out)
{
#pragma clang fp contract(off)
  const int b = blockIdx.x;
  const int tid = threadIdx.x;
  const int lane = tid & 63;
  const int w = tid >> 6;            // 16 waves

  __shared__ float  e_s[SS][HH];     // 128 KB: e_g slice (read row-broadcast in E -> no pad needed)
  __shared__ double parts8[8][258];  // 16.5 KB padded partials (row stride 516 words)
  __shared__ float  u_s[SS];
  __shared__ float  gates_s[G4];
  __shared__ float  dec_s[EE], hy_s[HH], c_s[HH], gl_s[HH];
  __shared__ float  q4_s[4][132];    // replicated q (stride 132 -> 4 distinct banks across quarters)
  __shared__ float  vg4_s[4][132];   // replicated v_g
  __shared__ float  vp4_s[4][132];   // replicated v_p
  __shared__ float  bqg_s[HH], bqp_s[HH];
  __shared__ uint32_t keys0_s[TT], keys1_s[TT];  // per-t threefry keys (hoisted off critical path)
  __shared__ unsigned char mask_s[SS];
  __shared__ float  fred_s[4];
  __shared__ double dred_s[4];
  __shared__ float  amax_v[4];
  __shared__ int    amax_i[4];
  __shared__ int    idx_sh, fin_sh;

  const float* egb = e_g + (size_t)b*SS*HH;
  const float* epb = e_p + (size_t)b*SS*HH;

  // ---- one-time block init ----
  if (tid < HH){
    dec_s[tid] = dec0[b*EE + tid];
    hy_s[tid]  = h0v[b*HH + tid];
    c_s[tid]   = c0v[b*HH + tid];
    const float vgv = vg[tid];
    const float vpv = vp[tid];
    #pragma unroll
    for (int c=0;c<4;++c){ vg4_s[c][tid] = vgv; vp4_s[c][tid] = vpv; }
    bqg_s[tid] = bqg[tid];
    bqp_s[tid] = bqp[tid];
  }
  if (tid < SS) mask_s[tid] = 0;
  if (tid < TT){
    uint32_t kk0, kk1;
    threefry2x32(0u, 42u, 0u, (uint32_t)tid, &kk0, &kk1);   // key_t (partitionable split)
    keys0_s[tid] = kk0; keys1_s[tid] = kk1;
  }
  if (tid == 0) fin_sh = 1;
  // stage e_g slice into LDS (coalesced float4)
  for (int idx = tid; idx < SS*32; idx += 1024){
    const int r  = idx >> 5;
    const int c4 = (idx & 31) << 2;
    *(float4*)&e_s[r][c4] = ((const float4*)egb)[idx];
  }
  __syncthreads();

  // per-thread static maps: 4 threads per s-row, quarter-row each
  const int sD = tid >> 2;           // 0..255
  const int q4r = tid & 3;           // quarter: h = q4r*32 .. +31
  // register-resident e_g / e_p quarter-rows (constant across t)
  float eD[32], eG[32];
  #pragma unroll
  for (int i=0;i<32;++i) eD[i] = e_s[sD][q4r*32 + i];
  {
    const float4* epr = (const float4*)(epb + sD*HH + q4r*32);
    #pragma unroll
    for (int k=0;k<8;++k) *(float4*)&eG[4*k] = epr[k];
  }

  for (int t = 0; t < TT; ++t){
    // ---- A: gates GEMV split across thread halves; activation fused ----
    double* aux = &parts8[0][0];     // 512 f64 scratch (rows 0-1), free here
    double a0 = 0.0;
    if (tid < 512){
      const int j = tid;
      double p0=0.0,p1=0.0,p2=0.0,p3=0.0;
      #pragma unroll 4
      for (int e=0;e<EE;e+=4){
        p0 += (double)dec_s[e+0] * (double)WiT[(e+0)*G4 + j];
        p1 += (double)dec_s[e+1] * (double)WiT[(e+1)*G4 + j];
        p2 += (double)dec_s[e+2] * (double)WiT[(e+2)*G4 + j];
        p3 += (double)dec_s[e+3] * (double)WiT[(e+3)*G4 + j];
      }
      a0 = ((p0+p1)+p2)+p3;
    } else {
      const int j = tid - 512;
      double r0=0.0,r1=0.0,r2=0.0,r3=0.0;
      #pragma unroll 4
      for (int k=0;k<HH;k+=4){
        r0 += (double)hy_s[k+0] * (double)WhT[(k+0)*G4 + j];
        r1 += (double)hy_s[k+1] * (double)WhT[(k+1)*G4 + j];
        r2 += (double)hy_s[k+2] * (double)WhT[(k+2)*G4 + j];
        r3 += (double)hy_s[k+3] * (double)WhT[(k+3)*G4 + j];
      }
      aux[j] = ((r0+r1)+r2)+r3;
    }
    __syncthreads();
    if (tid < 512){
      const int j = tid;
      const float g = (float)a0 + bi[j] + (float)aux[j] + bh[j];
      gates_s[j] = ((j >> 7) == 2) ? xla_tanhf(g) : xla_sigmoidf(g);
    }
    __syncthreads();

    // ---- B2: LSTM combine ----
    if (tid < HH){
      const int h = tid;
      const float cn = gates_s[HH+h]*c_s[h] + gates_s[h]*gates_s[2*HH+h];
      const float hn = gates_s[3*HH+h]*xla_tanhf(cn);
      c_s[h] = cn; hy_s[h] = hn;
    }
    __syncthreads();

    // ---- C: q_g = hy @ Wq_g.T + bq_g (4x32-k f64 partials, bit-identical) ----
    if (tid < 512){
      const int o = tid & 127, qc = tid >> 7;
      const float* Wc = WqgT + o;
      double acc = 0.0;
      #pragma unroll 8
      for (int i=0;i<32;++i){ const int k = qc*32 + i; acc += (double)hy_s[k] * (double)Wc[(size_t)k*HH]; }
      parts8[qc][o] = acc;
    }
    __syncthreads();
    if (tid < HH){
      const float qq = (float)(((parts8[0][tid]+parts8[1][tid])+parts8[2][tid])+parts8[3][tid]) + bqg_s[tid];
      #pragma unroll
      for (int c=0;c<4;++c) q4_s[c][tid] = qq;
    }
    __syncthreads();

    // ---- D: u_g partials from register e_g (chunk boundaries = R5, bit-identical) ----
    const bool skipRow = (mask_s[sD] != 0);
    if (!skipRow){
      #pragma unroll
      for (int cc=0; cc<2; ++cc){
        const int hb = q4r*32 + cc*16;
        double acc = 0.0;
        #pragma unroll
        for (int i=0;i<16;++i){
          acc += (double)vg4_s[q4r][hb+i] * (double)xla_tanhf(q4_s[q4r][hb+i] + eD[cc*16+i]);
        }
        parts8[q4r*2 + cc][sD] = acc;
      }
    }
    __syncthreads();

    // ---- D combine + mask ----
    if (tid < SS){
      float uf;
      if (mask_s[tid]) uf = NEG_INF_F;
      else {
        double u = 0.0;
        #pragma unroll
        for (int wi=0;wi<8;++wi) u += parts8[wi][tid];
        uf = (float)u;
      }
      u_s[tid] = uf;
    }
    __syncthreads();

    // ---- softmax #1 -> a in u_s ----
    {
      float x = 0.0f;
      if (tid < SS){
        x = u_s[tid];
        float wm = x;
        #pragma unroll
        for (int off=32; off; off>>=1) wm = fmaxf(wm, __shfl_xor(wm, off, 64));
        if (lane == 0) fred_s[w] = wm;
      }
      __syncthreads();
      const float m = fmaxf(fmaxf(fred_s[0], fred_s[1]), fmaxf(fred_s[2], fred_s[3]));
      float p = 0.0f;
      if (tid < SS){
        p = mask_s[tid] ? 0.0f : expf(x - m);
        const double zs = wave_sum_f64((double)p);
        if (lane == 0) dred_s[w] = zs;
      }
      __syncthreads();
      const float Z = (float)(dred_s[0] + dred_s[1] + dred_s[2] + dred_s[3]);
      if (tid < SS) u_s[tid] = p / Z;
    }
    __syncthreads();

    // ---- E: g_l[h] = Σ_s a[s]*e_g[s,h] from LDS (8x32-s f64 partials; masked a == +0.0 exact) ----
    {
      const int h = tid & 127, p8 = tid >> 7;
      double acc = 0.0;
      #pragma unroll 8
      for (int sl=0; sl<32; ++sl){
        const int s = p8*32 + sl;
        acc += (double)u_s[s] * (double)e_s[s][h];
      }
      parts8[p8][h] = acc;
    }
    __syncthreads();
    if (tid < HH){
      double g = parts8[0][tid];
      #pragma unroll
      for (int p8=1;p8<8;++p8) g += parts8[p8][tid];
      gl_s[tid] = (float)g;
    }
    __syncthreads();

    // ---- F: q_p = g_l @ Wq_p.T + bq_p (bit-identical) ----
    if (tid < 512){
      const int o = tid & 127, qc = tid >> 7;
      const float* Wc = WqpT + o;
      double acc = 0.0;
      #pragma unroll 8
      for (int i=0;i<32;++i){ const int k = qc*32 + i; acc += (double)gl_s[k] * (double)Wc[(size_t)k*HH]; }
      parts8[qc][o] = acc;
    }
    __syncthreads();
    if (tid < HH){
      const float qq = (float)(((parts8[0][tid]+parts8[1][tid])+parts8[2][tid])+parts8[3][tid]) + bqp_s[tid];
      #pragma unroll
      for (int c=0;c<4;++c) q4_s[c][tid] = qq;
    }
    __syncthreads();

    // ---- G: u_p partials from register e_p (bit-identical chunking) ----
    if (!skipRow){
      #pragma unroll
      for (int cc=0; cc<2; ++cc){
        const int hb = q4r*32 + cc*16;
        double acc = 0.0;
        #pragma unroll
        for (int i=0;i<16;++i){
          acc += (double)vp4_s[q4r][hb+i] * (double)xla_tanhf(q4_s[q4r][hb+i] + eG[cc*16+i]);
        }
        parts8[q4r*2 + cc][sD] = acc;
      }
    }
    __syncthreads();

    float logit_x = NEG_INF_F;
    if (tid < SS){
      if (!mask_s[tid]){
        double u = 0.0;
        #pragma unroll
        for (int wi=0;wi<8;++wi) u += parts8[wi][tid];
        logit_x = 10.0f * xla_tanhf((float)u);
      }
    }

    // ---- softmax #2 -> probs out ----
    {
      const float x = logit_x;
      if (tid < SS){
        float wm = x;
        #pragma unroll
        for (int off=32; off; off>>=1) wm = fmaxf(wm, __shfl_xor(wm, off, 64));
        if (lane == 0) fred_s[w] = wm;
      }
      __syncthreads();
      const float m = fmaxf(fmaxf(fred_s[0], fred_s[1]), fmaxf(fred_s[2], fred_s[3]));
      float p = 0.0f;
      if (tid < SS){
        p = mask_s[tid] ? 0.0f : expf(x - m);
        const double zs = wave_sum_f64((double)p);
        if (lane == 0) dred_s[w] = zs;
      }
      __syncthreads();
      const float Z = (float)(dred_s[0] + dred_s[1] + dred_s[2] + dred_s[3]);
      if (tid < SS) probs_out[((size_t)t*BB + b)*SS + tid] = p / Z;
    }

    // ---- gumbel + argmax + state update ----
    {
      if (tid < SS){
        float y = -3.0e38f;
        if (!mask_s[tid]){
          uint32_t r0, r1;
          threefry2x32(keys0_s[t], keys1_s[t], 0u, (uint32_t)(b*SS + tid), &r0, &r1);
          const uint32_t bits = r0 ^ r1;
          const float f = __uint_as_float((bits >> 9) | 0x3f800000u) - 1.0f;
          const float u01 = fmaxf(TINY_F32, f);
          const float g = -logf(-logf(u01));
          y = logit_x + g;
        }
        int bi_ = tid;
        #pragma unroll
        for (int off=32; off; off>>=1){
          const float oy = __shfl_xor(y, off, 64);
          const int oi = __shfl_xor(bi_, off, 64);
          if (oy > y || (oy == y && oi < bi_)){ y = oy; bi_ = oi; }
        }
        if (lane == 0){ amax_v[w] = y; amax_i[w] = bi_; }
      }
      __syncthreads();
      if (tid == 0){
        float bv = amax_v[0]; int bidx = amax_i[0];
        #pragma unroll
        for (int k=1;k<4;++k){
          if (amax_v[k] > bv || (amax_v[k] == bv && amax_i[k] < bidx)){ bv = amax_v[k]; bidx = amax_i[k]; }
        }
        const int fin = fin_sh;
        const int idx = fin ? bidx : 0;
        sels_out[(size_t)t*BB + b] = (float)idx;
        fin_sh = (fin && idx != 0) ? 1 : 0;
        mask_s[idx] = 1;
        mask_s[0] = 0;
        idx_sh = idx;
      }
      __syncthreads();
      if (tid < EE){
        dec_s[tid] = emb[((size_t)idx_sh*BB + b)*EE + tid];
      }
    }
    __syncthreads();   // dec_s/mask_s ready for next step
  }

  // ---- final state write ----
  if (tid < HH){
    hx_out[b*HH + tid] = hy_s[tid];
    cx_out[b*HH + tid] = c_s[tid];
  }
}

__global__ void ws_fail_kernel(float* sels_out){
  if (threadIdx.x == 0 && blockIdx.x == 0) sels_out[0] = -77777.0f;
}

extern "C" void kernel_launch(void* const* d_in, const int* in_sizes, int n_in,
                              void* d_out, int out_size, void* d_ws, size_t ws_size,
                              hipStream_t stream)
{
  const float* decoder_input = (const float*)d_in[0];
  const float* embedded      = (const float*)d_in[1];
  const float* h0            = (const float*)d_in[2];
  const float* c0            = (const float*)d_in[3];
  const float* context       = (const float*)d_in[4];
  const float* Wi            = (const float*)d_in[5];
  const float* bi            = (const float*)d_in[6];
  const float* Wh            = (const float*)d_in[7];
  const float* bh            = (const float*)d_in[8];
  const float* Wq_g          = (const float*)d_in[9];
  const float* bq_g          = (const float*)d_in[10];
  const float* Wref_g        = (const float*)d_in[11];
  const float* bref_g        = (const float*)d_in[12];
  const float* v_g           = (const float*)d_in[13];
  const float* Wq_p          = (const float*)d_in[14];
  const float* bq_p          = (const float*)d_in[15];
  const float* Wref_p        = (const float*)d_in[16];
  const float* bref_p        = (const float*)d_in[17];
  const float* v_p           = (const float*)d_in[18];

  char* ws = (char*)d_ws;
  size_t off = 0;
  auto alloc = [&](size_t bytes) -> void* {
    void* p = ws + off;
    off += (bytes + 255) & ~(size_t)255;
    return p;
  };
  float* e_g   = (float*)alloc((size_t)BB*SS*HH*4);
  float* e_p   = (float*)alloc((size_t)BB*SS*HH*4);
  float* WiT   = (float*)alloc((size_t)EE*G4*4);
  float* WhT   = (float*)alloc((size_t)HH*G4*4);
  float* WqgT  = (float*)alloc((size_t)HH*HH*4);
  float* WqpT  = (float*)alloc((size_t)HH*HH*4);

  float* probs_out = (float*)d_out;                  // (T,B,S)
  float* sels_out  = probs_out + (size_t)TT*BB*SS;   // (T,B)
  float* hx_out    = sels_out + (size_t)TT*BB;       // (B,H)
  float* cx_out    = hx_out + (size_t)BB*HH;         // (B,H)

  if (off > ws_size){
    ws_fail_kernel<<<1, 64, 0, stream>>>(sels_out);
    return;
  }

  transpose_weights_kernel<<<(G4*EE + 255)/256, 256, 0, stream>>>(
      Wi, Wh, Wq_g, Wq_p, WiT, WhT, WqgT, WqpT);
  precompute_e_kernel<<<(SS*BB)/64, 256, 0, stream>>>(context, Wref_g, bref_g, e_g);
  precompute_e_kernel<<<(SS*BB)/64, 256, 0, stream>>>(context, Wref_p, bref_p, e_p);

  decode_kernel<<<BB, 1024, 0, stream>>>(
      decoder_input, h0, c0,
      WiT, WhT, bi, bh,
      WqgT, bq_g, v_g,
      WqpT, bq_p, v_p,
      e_g, e_p, embedded,
      probs_out, sels_out, hx_out, cx_out);
}